// Round 1
// baseline (12789.602 us; speedup 1.0000x reference)
//
#include <hip/hip_runtime.h>

// ---------------------------------------------------------------------------
// PillarResNet18 forward (masked dense convs), fp32 exact baseline.
// Layers: conv3x3(+BN scale/shift)(+mask)(+residual)(+relu), mask maxpool.
// ---------------------------------------------------------------------------

#define F_RELU 1
#define F_MASK 2
#define F_RES  4

// mask = (mask_p < 0.1); x0 = x * mask. Threads over B*H*W, loop channels.
__global__ void mask_and_mul(const float* __restrict__ x,
                             const float* __restrict__ mask_p,
                             float* __restrict__ m, float* __restrict__ x0,
                             int B, int C, int HW) {
    int i = blockIdx.x * blockDim.x + threadIdx.x;
    if (i >= B * HW) return;
    int b = i / HW;
    int p = i - b * HW;
    float mv = (mask_p[i] < 0.1f) ? 1.0f : 0.0f;
    m[i] = mv;
    const float* xb = x + (size_t)b * C * HW + p;
    float* ob = x0 + (size_t)b * C * HW + p;
    for (int c = 0; c < C; ++c) ob[(size_t)c * HW] = xb[(size_t)c * HW] * mv;
}

// 3x3 stride-2 pad-1 max-pool on the (B,1,H,W) mask.
__global__ void mask_down(const float* __restrict__ mi, float* __restrict__ mo,
                          int B, int Hi, int Wi, int Ho, int Wo) {
    int i = blockIdx.x * blockDim.x + threadIdx.x;
    if (i >= B * Ho * Wo) return;
    int wo = i % Wo;
    int t = i / Wo;
    int ho = t % Ho;
    int b = t / Ho;
    float v = 0.0f;
    #pragma unroll
    for (int kh = 0; kh < 3; ++kh) {
        int hi = ho * 2 + kh - 1;
        if (hi < 0 || hi >= Hi) continue;
        #pragma unroll
        for (int kw = 0; kw < 3; ++kw) {
            int wi = wo * 2 + kw - 1;
            if (wi < 0 || wi >= Wi) continue;
            v = fmaxf(v, mi[((size_t)b * Hi + hi) * Wi + wi]);
        }
    }
    mo[i] = v;
}

// Generic fused conv3x3 (pad 1, stride 1 or 2):
//   acc = conv(in, wgt); v = acc*s[co]+t[co]; [v *= mask]; [v += res]; [relu]
// Each thread: one output pixel, COPT consecutive output channels.
template <int COPT>
__global__ void conv3x3(const float* __restrict__ in, const float* __restrict__ wgt,
                        const float* __restrict__ s, const float* __restrict__ t,
                        const float* __restrict__ mask, const float* __restrict__ res,
                        float* __restrict__ out,
                        int Cin, int Cout, int Hin, int Win, int Hout, int Wout,
                        int stride, int flags) {
    int idx = blockIdx.x * blockDim.x + threadIdx.x;
    int HWo = Hout * Wout;
    if (idx >= HWo) return;
    int wo = idx % Wout;
    int ho = idx / Wout;
    int co0 = blockIdx.y * COPT;
    int b = blockIdx.z;

    float acc[COPT];
    #pragma unroll
    for (int c = 0; c < COPT; ++c) acc[c] = 0.0f;

    const float* inb = in + (size_t)b * Cin * Hin * Win;
    const int wstride = Cin * 9;  // per-output-channel weight stride

    for (int ci = 0; ci < Cin; ++ci) {
        const float* ip = inb + (size_t)ci * Hin * Win;
        const float* wp = wgt + (size_t)(co0 * Cin + ci) * 9;
        #pragma unroll
        for (int kh = 0; kh < 3; ++kh) {
            int hi = ho * stride + kh - 1;
            if (hi < 0 || hi >= Hin) continue;
            #pragma unroll
            for (int kw = 0; kw < 3; ++kw) {
                int wi = wo * stride + kw - 1;
                if (wi < 0 || wi >= Win) continue;
                float v = ip[(size_t)hi * Win + wi];
                #pragma unroll
                for (int c = 0; c < COPT; ++c)
                    acc[c] = fmaf(v, wp[(size_t)c * wstride + kh * 3 + kw], acc[c]);
            }
        }
    }

    float mv = (flags & F_MASK) ? mask[(size_t)b * HWo + idx] : 1.0f;
    #pragma unroll
    for (int c = 0; c < COPT; ++c) {
        int co = co0 + c;
        float v = acc[c] * s[co] + t[co];
        if (flags & F_MASK) v *= mv;
        if (flags & F_RES)  v += res[((size_t)b * Cout + co) * HWo + idx];
        if (flags & F_RELU) v = fmaxf(v, 0.0f);
        out[((size_t)b * Cout + co) * HWo + idx] = v;
    }
}

extern "C" void kernel_launch(void* const* d_in, const int* in_sizes, int n_in,
                              void* d_out, int out_size, void* d_ws, size_t ws_size,
                              hipStream_t stream) {
    const int B = 2;

    const float* x      = (const float*)d_in[0];   // (2,32,512,512)
    const float* mask_p = (const float*)d_in[1];   // (2,1,512,512)
    const float* w1  = (const float*)d_in[2];      // (5,32,32,3,3)
    const float* s1  = (const float*)d_in[3];      // (5,32)
    const float* t1  = (const float*)d_in[4];
    const float* wd2 = (const float*)d_in[5];      // (64,32,3,3)
    const float* w2  = (const float*)d_in[6];      // (4,64,64,3,3)
    const float* s2  = (const float*)d_in[7];      // (5,64)
    const float* t2  = (const float*)d_in[8];
    const float* wd3 = (const float*)d_in[9];      // (128,64,3,3)
    const float* w3  = (const float*)d_in[10];     // (4,128,128,3,3)
    const float* s3  = (const float*)d_in[11];     // (5,128)
    const float* t3  = (const float*)d_in[12];
    const float* wd4 = (const float*)d_in[13];     // (256,128,3,3)
    const float* w4  = (const float*)d_in[14];     // (4,256,256,3,3)
    const float* s4  = (const float*)d_in[15];     // (5,256)
    const float* t4  = (const float*)d_in[16];
    const float* w5  = (const float*)d_in[17];     // (3,256,256,3,3)
    const float* s5  = (const float*)d_in[18];     // (3,256)
    const float* t5  = (const float*)d_in[19];

    // ---- d_out slices (fp32, concatenated x1..x5) ----
    float* x1o = (float*)d_out;                      // 2*32*512*512 = 16777216
    float* x2o = x1o + 16777216;                     // 2*64*256*256 =  8388608
    float* x3o = x2o + 8388608;                      // 2*128*128*128 = 4194304
    float* x4o = x3o + 4194304;                      // 2*256*64*64  =  2097152
    float* x5o = x4o + 2097152;                      // 2*256*32*32  =   524288

    // ---- workspace layout (floats) ----
    float* ws = (float*)d_ws;
    float* m1 = ws;                 // 2*512*512 = 524288
    float* m2 = m1 + 524288;        // 2*256*256 = 131072
    float* m3 = m2 + 131072;        // 2*128*128 =  32768
    float* m4 = m3 + 32768;         // 2*64*64   =   8192
    float* A  = m4 + 8192;          // 16777216 (64 MB)
    float* Bb = A + 16777216;       // 16777216 (64 MB)

    auto conv = [&](const float* in, const float* wgt, const float* sp, const float* tp,
                    const float* mk, const float* rs, float* out,
                    int Cin, int Cout, int Hin, int Win, int stride, int flags) {
        int Hout = Hin / stride, Wout = Win / stride;
        int HWo = Hout * Wout;
        dim3 grid((HWo + 255) / 256, Cout / 4, B);
        conv3x3<4><<<grid, 256, 0, stream>>>(in, wgt, sp, tp, mk, rs, out,
                                             Cin, Cout, Hin, Win, Hout, Wout, stride, flags);
    };

    // ---- masks + x0 ----
    {
        int n = B * 512 * 512;
        mask_and_mul<<<(n + 255) / 256, 256, 0, stream>>>(x, mask_p, m1, A, B, 32, 512 * 512);
        mask_down<<<(B * 256 * 256 + 255) / 256, 256, 0, stream>>>(m1, m2, B, 512, 512, 256, 256);
        mask_down<<<(B * 128 * 128 + 255) / 256, 256, 0, stream>>>(m2, m3, B, 256, 256, 128, 128);
        mask_down<<<(B * 64 * 64 + 255) / 256, 256, 0, stream>>>(m3, m4, B, 128, 128, 64, 64);
    }

    const int W9_32  = 32 * 32 * 9;
    const int W9_64  = 64 * 64 * 9;
    const int W9_128 = 128 * 128 * 9;
    const int W9_256 = 256 * 256 * 9;

    // ---- stage 1 (32ch, 512x512) ----
    // conv0: B = relu(subm(A))
    conv(A,  w1 + 0 * W9_32, s1 + 0,   t1 + 0,   m1, nullptr, Bb, 32, 32, 512, 512, 1, F_RELU | F_MASK);
    // block1: A = relu(subm(B)); B = relu(subm(A) + B)
    conv(Bb, w1 + 1 * W9_32, s1 + 32,  t1 + 32,  m1, nullptr, A,  32, 32, 512, 512, 1, F_RELU | F_MASK);
    conv(A,  w1 + 2 * W9_32, s1 + 64,  t1 + 64,  m1, Bb,      Bb, 32, 32, 512, 512, 1, F_RELU | F_MASK | F_RES);
    // block2: A = relu(subm(B)); x1 = relu(subm(A) + B)
    conv(Bb, w1 + 3 * W9_32, s1 + 96,  t1 + 96,  m1, nullptr, A,  32, 32, 512, 512, 1, F_RELU | F_MASK);
    conv(A,  w1 + 4 * W9_32, s1 + 128, t1 + 128, m1, Bb,      x1o, 32, 32, 512, 512, 1, F_RELU | F_MASK | F_RES);

    // ---- stage 2 (32->64, 512->256) ----
    conv(x1o, wd2,            s2 + 0,   t2 + 0,   m2, nullptr, A,  32, 64, 512, 512, 2, F_RELU | F_MASK);
    conv(A,  w2 + 0 * W9_64,  s2 + 64,  t2 + 64,  m2, nullptr, Bb, 64, 64, 256, 256, 1, F_RELU | F_MASK);
    conv(Bb, w2 + 1 * W9_64,  s2 + 128, t2 + 128, m2, A,       A,  64, 64, 256, 256, 1, F_RELU | F_MASK | F_RES);
    conv(A,  w2 + 2 * W9_64,  s2 + 192, t2 + 192, m2, nullptr, Bb, 64, 64, 256, 256, 1, F_RELU | F_MASK);
    conv(Bb, w2 + 3 * W9_64,  s2 + 256, t2 + 256, m2, A,       x2o, 64, 64, 256, 256, 1, F_RELU | F_MASK | F_RES);

    // ---- stage 3 (64->128, 256->128) ----
    conv(x2o, wd3,            s3 + 0,   t3 + 0,   m3, nullptr, A,  64, 128, 256, 256, 2, F_RELU | F_MASK);
    conv(A,  w3 + 0 * W9_128, s3 + 128, t3 + 128, m3, nullptr, Bb, 128, 128, 128, 128, 1, F_RELU | F_MASK);
    conv(Bb, w3 + 1 * W9_128, s3 + 256, t3 + 256, m3, A,       A,  128, 128, 128, 128, 1, F_RELU | F_MASK | F_RES);
    conv(A,  w3 + 2 * W9_128, s3 + 384, t3 + 384, m3, nullptr, Bb, 128, 128, 128, 128, 1, F_RELU | F_MASK);
    conv(Bb, w3 + 3 * W9_128, s3 + 512, t3 + 512, m3, A,       x3o, 128, 128, 128, 128, 1, F_RELU | F_MASK | F_RES);

    // ---- stage 4 (128->256, 128->64) ----
    conv(x3o, wd4,            s4 + 0,    t4 + 0,    m4, nullptr, A,  128, 256, 128, 128, 2, F_RELU | F_MASK);
    conv(A,  w4 + 0 * W9_256, s4 + 256,  t4 + 256,  m4, nullptr, Bb, 256, 256, 64, 64, 1, F_RELU | F_MASK);
    conv(Bb, w4 + 1 * W9_256, s4 + 512,  t4 + 512,  m4, A,       A,  256, 256, 64, 64, 1, F_RELU | F_MASK | F_RES);
    conv(A,  w4 + 2 * W9_256, s4 + 768,  t4 + 768,  m4, nullptr, Bb, 256, 256, 64, 64, 1, F_RELU | F_MASK);
    conv(Bb, w4 + 3 * W9_256, s4 + 1024, t4 + 1024, m4, A,       x4o, 256, 256, 64, 64, 1, F_RELU | F_MASK | F_RES);

    // ---- conv5 (dense, 64->32) ----
    conv(x4o, w5 + 0 * W9_256, s5 + 0,   t5 + 0,   nullptr, nullptr, A,  256, 256, 64, 64, 2, F_RELU);
    conv(A,   w5 + 1 * W9_256, s5 + 256, t5 + 256, nullptr, nullptr, Bb, 256, 256, 32, 32, 1, F_RELU);
    conv(Bb,  w5 + 2 * W9_256, s5 + 512, t5 + 512, nullptr, nullptr, x5o, 256, 256, 32, 32, 1, F_RELU);
}

// Round 2
// 3132.847 us; speedup vs baseline: 4.0824x; 4.0824x over previous
//
#include <hip/hip_runtime.h>

#define F_RELU 1
#define F_MASK 2
#define F_RES  4

typedef __attribute__((ext_vector_type(8))) short bf16x8;
typedef __attribute__((ext_vector_type(4))) float f32x4;

__device__ __forceinline__ short f2bf(float x){
    union { float f; unsigned u; } v; v.f = x;
    unsigned r = v.u + 0x7FFFu + ((v.u >> 16) & 1u);
    return (short)(r >> 16);
}
__device__ __forceinline__ float bf2f(short h){
    union { float f; unsigned u; } v; v.u = ((unsigned)(unsigned short)h) << 16;
    return v.f;
}

// mask = (mask_p < 0.1); x0 = x * mask
__global__ void mask_and_mul(const float* __restrict__ x,
                             const float* __restrict__ mask_p,
                             float* __restrict__ m, float* __restrict__ x0,
                             int B, int C, int HW) {
    int i = blockIdx.x * blockDim.x + threadIdx.x;
    if (i >= B * HW) return;
    int b = i / HW;
    int p = i - b * HW;
    float mv = (mask_p[i] < 0.1f) ? 1.0f : 0.0f;
    m[i] = mv;
    const float* xb = x + (size_t)b * C * HW + p;
    float* ob = x0 + (size_t)b * C * HW + p;
    for (int c = 0; c < C; ++c) ob[(size_t)c * HW] = xb[(size_t)c * HW] * mv;
}

// 3x3 stride-2 pad-1 max-pool on (B,1,H,W) mask
__global__ void mask_down(const float* __restrict__ mi, float* __restrict__ mo,
                          int B, int Hi, int Wi, int Ho, int Wo) {
    int i = blockIdx.x * blockDim.x + threadIdx.x;
    if (i >= B * Ho * Wo) return;
    int wo = i % Wo;
    int t = i / Wo;
    int ho = t % Ho;
    int b = t / Ho;
    float v = 0.0f;
    #pragma unroll
    for (int kh = 0; kh < 3; ++kh) {
        int hi = ho * 2 + kh - 1;
        if (hi < 0 || hi >= Hi) continue;
        #pragma unroll
        for (int kw = 0; kw < 3; ++kw) {
            int wi = wo * 2 + kw - 1;
            if (wi < 0 || wi >= Wi) continue;
            v = fmaxf(v, mi[((size_t)b * Hi + hi) * Wi + wi]);
        }
    }
    mo[i] = v;
}

// Reorder weights W[co][ci][3][3] (fp32) -> rw[chunk][co][{hi:32,lo:32}] (bf16),
// chunk = tap*(Cin/32)+cic, k-in-chunk = ci%32.  One thread per (chunk,co,kk).
__global__ void reorder_w(const float* __restrict__ w, short* __restrict__ rw,
                          int Cin, int Cout) {
    int idx = blockIdx.x * 256 + threadIdx.x;
    int total = Cout * Cin * 9;
    if (idx >= total) return;
    int kk = idx & 31;
    int rest = idx >> 5;
    int co = rest % Cout;
    int chunk = rest / Cout;
    int cicn = Cin >> 5;
    int tap = chunk / cicn, cic = chunk - tap * cicn;
    int ci = cic * 32 + kk;
    float x = w[((size_t)co * Cin + ci) * 9 + tap];
    short h = f2bf(x);
    short l = f2bf(x - bf2f(h));
    size_t o = ((size_t)(chunk * Cout + co)) * 64;
    rw[o + kk] = h;
    rw[o + 32 + kk] = l;
}

// Implicit-GEMM conv3x3 (pad1, stride 1/2) with bf16x3 split MFMA.
// M = Cout (BM per block), N = BN pixels (TH x TW spatial tile), K = 9*Cin.
template<int BM, int BN>
__global__ __launch_bounds__(256, 2)
void conv_mfma(const float* __restrict__ in, const short* __restrict__ rw,
               const float* __restrict__ s, const float* __restrict__ t,
               const float* __restrict__ mask, const float* __restrict__ res,
               float* __restrict__ out,
               int Cin, int Cout, int Hin, int Win, int Hout, int Wout,
               int TH, int TW, int stride, int flags)
{
    constexpr int WM = (BM >= 64) ? BM / 2 : BM;
    constexpr int WAVES_M = BM / WM;
    constexpr int WAVES_N = 4 / WAVES_M;
    constexpr int WN = BN / WAVES_N;
    constexpr int MR = WM / 16;
    constexpr int NR = WN / 16;
    constexpr int ELEMS = (32 * BN) / 256;   // staged elems per thread per chunk
    constexpr int LDST = 40;                 // padded row stride (bf16 units)

    __shared__ short Bh[BN * LDST];
    __shared__ short Bl[BN * LDST];

    const int tid = threadIdx.x;
    const int lane = tid & 63;
    const int wv = tid >> 6;
    const int wm = wv / WAVES_N;
    const int wn = wv % WAVES_N;

    const int tilesX = Wout / TW;
    const int oy0 = (blockIdx.x / tilesX) * TH;
    const int ox0 = (blockIdx.x % tilesX) * TW;
    const int co0 = blockIdx.y * BM;
    const int b = blockIdx.z;

    const int HWin = Hin * Win;
    const int HWo = Hout * Wout;
    const float* inb = in + (size_t)b * Cin * HWin;

    // staging coords: thread covers pixel sn, k = kb..kb+ELEMS-1
    const int sn = tid & (BN - 1);
    const int kb = (tid / BN) * ELEMS;
    const int sty = sn / TW;
    const int stx = sn - sty * TW;
    const int soy = oy0 + sty;
    const int sox = ox0 + stx;

    const int cicn = Cin >> 5;
    const int nChunks = 9 * cicn;

    f32x4 acc[MR][NR];
    #pragma unroll
    for (int m = 0; m < MR; ++m)
        #pragma unroll
        for (int n = 0; n < NR; ++n)
            #pragma unroll
            for (int r = 0; r < 4; ++r) acc[m][n][r] = 0.0f;

    auto LOADG = [&](int c, float* dst) {
        int tap = c / cicn, cic = c - tap * cicn;
        int iy = soy * stride + (tap / 3) - 1;
        int ix = sox * stride + (tap - (tap / 3) * 3) - 1;
        bool ok = (iy >= 0 && iy < Hin && ix >= 0 && ix < Win);
        const float* p = inb + ((size_t)(cic * 32 + kb)) * HWin + (size_t)iy * Win + ix;
        #pragma unroll
        for (int i = 0; i < ELEMS; ++i) dst[i] = ok ? p[(size_t)i * HWin] : 0.0f;
    };
    auto WLDS = [&](const float* src) {
        const int sw = ((sn >> 3) & 3) << 3;
        #pragma unroll
        for (int i = 0; i < ELEMS; i += 2) {
            int k = kb + i;
            int idx = sn * LDST + (k ^ sw);
            short h0 = f2bf(src[i]),     h1 = f2bf(src[i + 1]);
            float r0 = src[i] - bf2f(h0), r1 = src[i + 1] - bf2f(h1);
            short l0 = f2bf(r0),         l1 = f2bf(r1);
            *(unsigned*)&Bh[idx] = ((unsigned)(unsigned short)h1 << 16) | (unsigned short)h0;
            *(unsigned*)&Bl[idx] = ((unsigned)(unsigned short)l1 << 16) | (unsigned short)l0;
        }
    };

    float v[ELEMS];
    LOADG(0, v);
    WLDS(v);
    __syncthreads();

    const int row = lane & 15, q = lane >> 4;

    for (int c = 0; c < nChunks; ++c) {
        float v2[ELEMS];
        if (c + 1 < nChunks) LOADG(c + 1, v2);

        bf16x8 ah[MR], al[MR], bh[NR], bl[NR];
        #pragma unroll
        for (int m = 0; m < MR; ++m) {
            int co = co0 + wm * WM + m * 16 + row;
            const short* ap = rw + ((size_t)(c * Cout + co)) * 64 + q * 8;
            ah[m] = *(const bf16x8*)ap;
            al[m] = *(const bf16x8*)(ap + 32);
        }
        #pragma unroll
        for (int n = 0; n < NR; ++n) {
            int nl = wn * WN + n * 16 + row;
            int kq = (q << 3) ^ (((nl >> 3) & 3) << 3);
            bh[n] = *(const bf16x8*)&Bh[nl * LDST + kq];
            bl[n] = *(const bf16x8*)&Bl[nl * LDST + kq];
        }
        #pragma unroll
        for (int m = 0; m < MR; ++m)
            #pragma unroll
            for (int n = 0; n < NR; ++n) {
                acc[m][n] = __builtin_amdgcn_mfma_f32_16x16x32_bf16(ah[m], bh[n], acc[m][n], 0, 0, 0);
                acc[m][n] = __builtin_amdgcn_mfma_f32_16x16x32_bf16(al[m], bh[n], acc[m][n], 0, 0, 0);
                acc[m][n] = __builtin_amdgcn_mfma_f32_16x16x32_bf16(ah[m], bl[n], acc[m][n], 0, 0, 0);
            }
        __syncthreads();
        if (c + 1 < nChunks) WLDS(v2);
        __syncthreads();
    }

    // epilogue: D row = co (= q*4+r within 16), D col = pixel (= lane&15)
    int pix[NR]; float mv[NR];
    #pragma unroll
    for (int n = 0; n < NR; ++n) {
        int nl = wn * WN + n * 16 + row;
        int ty = nl / TW, tx = nl - ty * TW;
        pix[n] = (oy0 + ty) * Wout + (ox0 + tx);
        mv[n] = (flags & F_MASK) ? mask[(size_t)b * HWo + pix[n]] : 1.0f;
    }
    #pragma unroll
    for (int m = 0; m < MR; ++m) {
        #pragma unroll
        for (int r = 0; r < 4; ++r) {
            int co = co0 + wm * WM + m * 16 + q * 4 + r;
            float sc = s[co], sh = t[co];
            size_t ob = ((size_t)b * Cout + co) * HWo;
            #pragma unroll
            for (int n = 0; n < NR; ++n) {
                float val = acc[m][n][r] * sc + sh;
                val *= mv[n];
                if (flags & F_RES) val += res[ob + pix[n]];
                if (flags & F_RELU) val = fmaxf(val, 0.0f);
                out[ob + pix[n]] = val;
            }
        }
    }
}

extern "C" void kernel_launch(void* const* d_in, const int* in_sizes, int n_in,
                              void* d_out, int out_size, void* d_ws, size_t ws_size,
                              hipStream_t stream) {
    const int B = 2;

    const float* x      = (const float*)d_in[0];
    const float* mask_p = (const float*)d_in[1];
    const float* w1  = (const float*)d_in[2];
    const float* s1  = (const float*)d_in[3];
    const float* t1  = (const float*)d_in[4];
    const float* wd2 = (const float*)d_in[5];
    const float* w2  = (const float*)d_in[6];
    const float* s2  = (const float*)d_in[7];
    const float* t2  = (const float*)d_in[8];
    const float* wd3 = (const float*)d_in[9];
    const float* w3  = (const float*)d_in[10];
    const float* s3  = (const float*)d_in[11];
    const float* t3  = (const float*)d_in[12];
    const float* wd4 = (const float*)d_in[13];
    const float* w4  = (const float*)d_in[14];
    const float* s4  = (const float*)d_in[15];
    const float* t4  = (const float*)d_in[16];
    const float* w5  = (const float*)d_in[17];
    const float* s5  = (const float*)d_in[18];
    const float* t5  = (const float*)d_in[19];

    // d_out slices
    float* x1o = (float*)d_out;
    float* x2o = x1o + 16777216;
    float* x3o = x2o + 8388608;
    float* x4o = x3o + 4194304;
    float* x5o = x4o + 2097152;

    // workspace: [ rw bf16 weights | m1 m2 m3 m4 | A | Bb ]
    float* ws = (float*)d_ws;
    short* rwbase = (short*)d_ws;
    const size_t RW_FLOATS = 5299200;       // 10,598,400 shorts exactly
    float* m1 = ws + RW_FLOATS;             // 524288
    float* m2 = m1 + 524288;                // 131072
    float* m3 = m2 + 131072;                // 32768
    float* m4 = m3 + 32768;                 // 8192
    float* A  = m4 + 8192;                  // 16777216
    float* Bb = A + 16777216;               // 16777216

    size_t ro = 0;
    auto reord = [&](const float* wsrc, int Cin, int Cout) -> const short* {
        short* dst = rwbase + ro;
        int total = Cout * Cin * 9;
        reorder_w<<<(total + 255) / 256, 256, 0, stream>>>(wsrc, dst, Cin, Cout);
        ro += (size_t)total * 2;
        return dst;
    };

    const short* r1[5]; for (int i = 0; i < 5; ++i) r1[i] = reord(w1 + (size_t)i * 9216, 32, 32);
    const short* rd2 = reord(wd2, 32, 64);
    const short* r2[4]; for (int i = 0; i < 4; ++i) r2[i] = reord(w2 + (size_t)i * 36864, 64, 64);
    const short* rd3 = reord(wd3, 64, 128);
    const short* r3[4]; for (int i = 0; i < 4; ++i) r3[i] = reord(w3 + (size_t)i * 147456, 128, 128);
    const short* rd4 = reord(wd4, 128, 256);
    const short* r4[4]; for (int i = 0; i < 4; ++i) r4[i] = reord(w4 + (size_t)i * 589824, 256, 256);
    const short* r5[3]; for (int i = 0; i < 3; ++i) r5[i] = reord(w5 + (size_t)i * 589824, 256, 256);

    // masks + x0
    {
        int n = B * 512 * 512;
        mask_and_mul<<<(n + 255) / 256, 256, 0, stream>>>(x, mask_p, m1, A, B, 32, 512 * 512);
        mask_down<<<(B * 256 * 256 + 255) / 256, 256, 0, stream>>>(m1, m2, B, 512, 512, 256, 256);
        mask_down<<<(B * 128 * 128 + 255) / 256, 256, 0, stream>>>(m2, m3, B, 256, 256, 128, 128);
        mask_down<<<(B * 64 * 64 + 255) / 256, 256, 0, stream>>>(m3, m4, B, 128, 128, 64, 64);
    }

    auto conv = [&](const float* in, const short* rwp, const float* sp, const float* tp,
                    const float* mk, const float* rs, float* outp,
                    int Cin, int Cout, int Hin, int Win, int stride, int flags,
                    int BM, int BN) {
        int Hout = Hin / stride, Wout = Win / stride, HWo = Hout * Wout;
        int TW = (Wout < BN) ? Wout : BN;
        int TH = BN / TW;
        dim3 grid(HWo / BN, Cout / BM, B);
        if (BM == 32 && BN == 128)
            conv_mfma<32, 128><<<grid, 256, 0, stream>>>(in, rwp, sp, tp, mk, rs, outp,
                Cin, Cout, Hin, Win, Hout, Wout, TH, TW, stride, flags);
        else if (BM == 64 && BN == 128)
            conv_mfma<64, 128><<<grid, 256, 0, stream>>>(in, rwp, sp, tp, mk, rs, outp,
                Cin, Cout, Hin, Win, Hout, Wout, TH, TW, stride, flags);
        else if (BM == 128 && BN == 64)
            conv_mfma<128, 64><<<grid, 256, 0, stream>>>(in, rwp, sp, tp, mk, rs, outp,
                Cin, Cout, Hin, Win, Hout, Wout, TH, TW, stride, flags);
        else
            conv_mfma<64, 64><<<grid, 256, 0, stream>>>(in, rwp, sp, tp, mk, rs, outp,
                Cin, Cout, Hin, Win, Hout, Wout, TH, TW, stride, flags);
    };

    // ---- stage 1 (32ch, 512x512): A(x0), Bb ping-pong ----
    conv(A,  r1[0], s1 + 0,   t1 + 0,   m1, nullptr, Bb,  32, 32, 512, 512, 1, F_RELU | F_MASK, 32, 128);
    conv(Bb, r1[1], s1 + 32,  t1 + 32,  m1, nullptr, A,   32, 32, 512, 512, 1, F_RELU | F_MASK, 32, 128);
    conv(A,  r1[2], s1 + 64,  t1 + 64,  m1, Bb,      Bb,  32, 32, 512, 512, 1, F_RELU | F_MASK | F_RES, 32, 128);
    conv(Bb, r1[3], s1 + 96,  t1 + 96,  m1, nullptr, A,   32, 32, 512, 512, 1, F_RELU | F_MASK, 32, 128);
    conv(A,  r1[4], s1 + 128, t1 + 128, m1, Bb,      x1o, 32, 32, 512, 512, 1, F_RELU | F_MASK | F_RES, 32, 128);

    // ---- stage 2 (32->64, 512->256) ----
    conv(x1o, rd2,   s2 + 0,   t2 + 0,   m2, nullptr, A,   32, 64, 512, 512, 2, F_RELU | F_MASK, 64, 128);
    conv(A,   r2[0], s2 + 64,  t2 + 64,  m2, nullptr, Bb,  64, 64, 256, 256, 1, F_RELU | F_MASK, 64, 128);
    conv(Bb,  r2[1], s2 + 128, t2 + 128, m2, A,       A,   64, 64, 256, 256, 1, F_RELU | F_MASK | F_RES, 64, 128);
    conv(A,   r2[2], s2 + 192, t2 + 192, m2, nullptr, Bb,  64, 64, 256, 256, 1, F_RELU | F_MASK, 64, 128);
    conv(Bb,  r2[3], s2 + 256, t2 + 256, m2, A,       x2o, 64, 64, 256, 256, 1, F_RELU | F_MASK | F_RES, 64, 128);

    // ---- stage 3 (64->128, 256->128) ----
    conv(x2o, rd3,   s3 + 0,   t3 + 0,   m3, nullptr, A,   64, 128, 256, 256, 2, F_RELU | F_MASK, 128, 64);
    conv(A,   r3[0], s3 + 128, t3 + 128, m3, nullptr, Bb, 128, 128, 128, 128, 1, F_RELU | F_MASK, 128, 64);
    conv(Bb,  r3[1], s3 + 256, t3 + 256, m3, A,       A,  128, 128, 128, 128, 1, F_RELU | F_MASK | F_RES, 128, 64);
    conv(A,   r3[2], s3 + 384, t3 + 384, m3, nullptr, Bb, 128, 128, 128, 128, 1, F_RELU | F_MASK, 128, 64);
    conv(Bb,  r3[3], s3 + 512, t3 + 512, m3, A,       x3o, 128, 128, 128, 128, 1, F_RELU | F_MASK | F_RES, 128, 64);

    // ---- stage 4 (128->256, 128->64) ----
    conv(x3o, rd4,   s4 + 0,    t4 + 0,    m4, nullptr, A,  128, 256, 128, 128, 2, F_RELU | F_MASK, 64, 64);
    conv(A,   r4[0], s4 + 256,  t4 + 256,  m4, nullptr, Bb, 256, 256, 64, 64, 1, F_RELU | F_MASK, 64, 64);
    conv(Bb,  r4[1], s4 + 512,  t4 + 512,  m4, A,       A,  256, 256, 64, 64, 1, F_RELU | F_MASK | F_RES, 64, 64);
    conv(A,   r4[2], s4 + 768,  t4 + 768,  m4, nullptr, Bb, 256, 256, 64, 64, 1, F_RELU | F_MASK, 64, 64);
    conv(Bb,  r4[3], s4 + 1024, t4 + 1024, m4, A,       x4o, 256, 256, 64, 64, 1, F_RELU | F_MASK | F_RES, 64, 64);

    // ---- conv5 (dense) ----
    conv(x4o, r5[0], s5 + 0,   t5 + 0,   nullptr, nullptr, A,   256, 256, 64, 64, 2, F_RELU, 64, 64);
    conv(A,   r5[1], s5 + 256, t5 + 256, nullptr, nullptr, Bb,  256, 256, 32, 32, 1, F_RELU, 64, 64);
    conv(Bb,  r5[2], s5 + 512, t5 + 512, nullptr, nullptr, x5o, 256, 256, 32, 32, 1, F_RELU, 64, 64);
}

// Round 4
// 1427.222 us; speedup vs baseline: 8.9612x; 2.1951x over previous
//
#include <hip/hip_runtime.h>

typedef __attribute__((ext_vector_type(8))) _Float16 f16x8;
typedef __attribute__((ext_vector_type(4))) _Float16 f16x4;
typedef __attribute__((ext_vector_type(4))) float f32x4;

// ---------------------------------------------------------------------------
// masks: m = (mask_p < 0.1); x0h = fp16 blocked [b][pix][32] of x*mask
// ---------------------------------------------------------------------------
__global__ void mask_make(const float* __restrict__ x, const float* __restrict__ mp,
                          float* __restrict__ m, _Float16* __restrict__ x0,
                          int B, int HW) {
    int i = blockIdx.x * blockDim.x + threadIdx.x;
    if (i >= B * HW) return;
    float mv = (mp[i] < 0.1f) ? 1.0f : 0.0f;
    m[i] = mv;
    int b = i / HW, p = i - b * HW;
    const float* xb = x + ((size_t)b * 32) * HW + p;
    _Float16* ob = x0 + (size_t)i * 32;
    #pragma unroll
    for (int c = 0; c < 32; ++c) ob[c] = (_Float16)(xb[(size_t)c * HW] * mv);
}

// 3x3 stride-2 pad-1 max-pool on (B,1,H,W) mask
__global__ void mask_down(const float* __restrict__ mi, float* __restrict__ mo,
                          int B, int Hi, int Wi, int Ho, int Wo) {
    int i = blockIdx.x * blockDim.x + threadIdx.x;
    if (i >= B * Ho * Wo) return;
    int wo = i % Wo;
    int t = i / Wo;
    int ho = t % Ho;
    int b = t / Ho;
    float v = 0.0f;
    #pragma unroll
    for (int kh = 0; kh < 3; ++kh) {
        int hi = ho * 2 + kh - 1;
        if (hi < 0 || hi >= Hi) continue;
        #pragma unroll
        for (int kw = 0; kw < 3; ++kw) {
            int wi = wo * 2 + kw - 1;
            if (wi < 0 || wi >= Wi) continue;
            v = fmaxf(v, mi[((size_t)b * Hi + hi) * Wi + wi]);
        }
    }
    mo[i] = v;
}

// Reorder weights W[co][ci][3][3] fp32 -> rw[chunk][co][32] fp16,
// chunk = tap*(Cin/32)+cic, k-in-chunk = ci%32.
__global__ void reorder_w(const float* __restrict__ w, _Float16* __restrict__ rw,
                          int Cin, int Cout) {
    int idx = blockIdx.x * 256 + threadIdx.x;
    int total = Cout * Cin * 9;
    if (idx >= total) return;
    int kk = idx & 31;
    int rest = idx >> 5;
    int co = rest % Cout;
    int chunk = rest / Cout;
    int cicn = Cin >> 5;
    int tap = chunk / cicn, cic = chunk - tap * cicn;
    int ci = cic * 32 + kk;
    rw[((size_t)(chunk * Cout + co)) * 32 + kk] = (_Float16)w[((size_t)co * Cin + ci) * 9 + tap];
}

// ---------------------------------------------------------------------------
// Implicit-GEMM conv3x3 (pad1, stride 1/2), fp16 MFMA, fp32 accumulate.
// M = Cout (BM/block), N = BN pixels, K = 9*Cin in 32-chunks (tap-major).
// Input/res/out16 are fp16 blocked [b][ci/32][pix][32]; out32 is NCHW fp32.
// LDS: [pixel][k] rows of LDST=40 halves (80B stride -> uniform banks for b128).
// ---------------------------------------------------------------------------
template<int BM, int BN>
__global__ __launch_bounds__(256, 2)
void conv_mfma(const _Float16* __restrict__ in, const _Float16* __restrict__ rw,
               const float* __restrict__ s, const float* __restrict__ t,
               const float* __restrict__ mask, const _Float16* __restrict__ res,
               float* __restrict__ out32, _Float16* __restrict__ out16,
               int Cin, int Cout, int Hin, int Win, int Hout, int Wout,
               int TH, int TW, int stride, int relu)
{
    constexpr int WM = (BM >= 64) ? BM / 2 : BM;
    constexpr int WAVES_M = BM / WM;
    constexpr int WAVES_N = 4 / WAVES_M;
    constexpr int WN = BN / WAVES_N;
    constexpr int MR = WM / 16;
    constexpr int NR = WN / 16;
    constexpr int ELEMS = (32 * BN) / 256;   // halves per thread per chunk
    constexpr int NV = ELEMS / 8;            // b128 ops per thread per chunk
    constexpr int LDST = 40;

    __shared__ _Float16 Bsm[2][BN * LDST];

    const int tid = threadIdx.x;
    const int lane = tid & 63;
    const int wv = tid >> 6;
    const int wm = wv / WAVES_N;
    const int wn = wv % WAVES_N;
    const int row = lane & 15, q = lane >> 4;

    const int tilesX = Wout / TW;
    const int oy0 = (blockIdx.x / tilesX) * TH;
    const int ox0 = (blockIdx.x % tilesX) * TW;
    const int co0 = blockIdx.y * BM;
    const int b = blockIdx.z;

    const int HWin = Hin * Win;
    const int HWo = Hout * Wout;
    const int cicn = Cin >> 5;
    const int cocn = Cout >> 5;
    const int nChunks = 9 * cicn;

    // staging coords: thread covers pixel sn, k = kb..kb+ELEMS-1
    const int sn = tid & (BN - 1);
    const int kb = (tid / BN) * ELEMS;
    const int sty = sn / TW;
    const int stx = sn - sty * TW;
    const int soy = oy0 + sty;
    const int sox = ox0 + stx;

    f32x4 acc[MR][NR];
    #pragma unroll
    for (int m = 0; m < MR; ++m)
        #pragma unroll
        for (int n = 0; n < NR; ++n)
            #pragma unroll
            for (int r = 0; r < 4; ++r) acc[m][n][r] = 0.0f;

    auto LOADG = [&](int c, f16x8* dst) {
        int tap = c / cicn, cic = c - tap * cicn;
        int iy = soy * stride + (tap / 3) - 1;
        int ix = sox * stride + (tap - (tap / 3) * 3) - 1;
        bool ok = (iy >= 0 && iy < Hin && ix >= 0 && ix < Win);
        const _Float16* p = in + (((size_t)(b * cicn + cic) * HWin + (size_t)iy * Win + ix) << 5) + kb;
        #pragma unroll
        for (int i = 0; i < NV; ++i) {
            if (ok) dst[i] = *(const f16x8*)(p + 8 * i);
            else    dst[i] = f16x8{};
        }
    };
    auto WLDS = [&](int buf, const f16x8* v) {
        #pragma unroll
        for (int i = 0; i < NV; ++i)
            *(f16x8*)&Bsm[buf][sn * LDST + kb + 8 * i] = v[i];
    };

    f16x8 v[NV];
    LOADG(0, v);
    WLDS(0, v);
    __syncthreads();

    for (int c = 0; c < nChunks; ++c) {
        f16x8 v2[NV];
        if (c + 1 < nChunks) LOADG(c + 1, v2);

        f16x8 ah[MR], bh[NR];
        #pragma unroll
        for (int m = 0; m < MR; ++m) {
            int co = co0 + wm * WM + m * 16 + row;
            ah[m] = *(const f16x8*)(rw + ((size_t)c * Cout + co) * 32 + (q << 3));
        }
        const _Float16* bp = &Bsm[c & 1][0];
        #pragma unroll
        for (int n = 0; n < NR; ++n) {
            int nl = wn * WN + n * 16 + row;
            bh[n] = *(const f16x8*)(bp + nl * LDST + (q << 3));
        }
        #pragma unroll
        for (int m = 0; m < MR; ++m)
            #pragma unroll
            for (int n = 0; n < NR; ++n)
                acc[m][n] = __builtin_amdgcn_mfma_f32_16x16x32_f16(ah[m], bh[n], acc[m][n], 0, 0, 0);

        if (c + 1 < nChunks) WLDS((c + 1) & 1, v2);
        __syncthreads();
    }

    // epilogue: D col = pixel (lane&15), D row = co (q*4+r)
    int pix[NR]; float mv[NR];
    #pragma unroll
    for (int n = 0; n < NR; ++n) {
        int nl = wn * WN + n * 16 + row;
        int ty = nl / TW, tx = nl - ty * TW;
        pix[n] = (oy0 + ty) * Wout + (ox0 + tx);
        mv[n] = mask ? mask[(size_t)b * HWo + pix[n]] : 1.0f;
    }
    #pragma unroll
    for (int m = 0; m < MR; ++m) {
        int cb = co0 + wm * WM + m * 16 + q * 4;   // base co for r=0..3
        float sc[4], sh[4];
        #pragma unroll
        for (int r = 0; r < 4; ++r) { sc[r] = s[cb + r]; sh[r] = t[cb + r]; }
        #pragma unroll
        for (int n = 0; n < NR; ++n) {
            size_t boff = ((size_t)(b * cocn + (cb >> 5)) * HWo + pix[n]) * 32 + (cb & 31);
            float val[4];
            #pragma unroll
            for (int r = 0; r < 4; ++r) {
                float x = acc[m][n][r] * sc[r] + sh[r];
                x *= mv[n];
                val[r] = x;
            }
            if (res) {
                f16x4 rv = *(const f16x4*)&res[boff];
                #pragma unroll
                for (int r = 0; r < 4; ++r) val[r] += (float)rv[r];
            }
            if (relu) {
                #pragma unroll
                for (int r = 0; r < 4; ++r) val[r] = fmaxf(val[r], 0.0f);
            }
            if (out16) {
                f16x4 pk;
                #pragma unroll
                for (int r = 0; r < 4; ++r) pk[r] = (_Float16)val[r];
                *(f16x4*)&out16[boff] = pk;
            }
            if (out32) {
                #pragma unroll
                for (int r = 0; r < 4; ++r)
                    out32[((size_t)b * Cout + cb + r) * HWo + pix[n]] = val[r];
            }
        }
    }
}

extern "C" void kernel_launch(void* const* d_in, const int* in_sizes, int n_in,
                              void* d_out, int out_size, void* d_ws, size_t ws_size,
                              hipStream_t stream) {
    const int B = 2;

    const float* x      = (const float*)d_in[0];
    const float* mask_p = (const float*)d_in[1];
    const float* w1  = (const float*)d_in[2];
    const float* s1  = (const float*)d_in[3];
    const float* t1  = (const float*)d_in[4];
    const float* wd2 = (const float*)d_in[5];
    const float* w2  = (const float*)d_in[6];
    const float* s2  = (const float*)d_in[7];
    const float* t2  = (const float*)d_in[8];
    const float* wd3 = (const float*)d_in[9];
    const float* w3  = (const float*)d_in[10];
    const float* s3  = (const float*)d_in[11];
    const float* t3  = (const float*)d_in[12];
    const float* wd4 = (const float*)d_in[13];
    const float* w4  = (const float*)d_in[14];
    const float* s4  = (const float*)d_in[15];
    const float* t4  = (const float*)d_in[16];
    const float* w5  = (const float*)d_in[17];
    const float* s5  = (const float*)d_in[18];
    const float* t5  = (const float*)d_in[19];

    // d_out slices (fp32 NCHW)
    float* x1o = (float*)d_out;
    float* x2o = x1o + 16777216;
    float* x3o = x2o + 8388608;
    float* x4o = x3o + 4194304;
    float* x5o = x4o + 2097152;

    // workspace: [ rw fp16 (5,299,200 halves) | m1..m4 fp32 | P Q R fp16 acts ]
    _Float16* rwbase = (_Float16*)d_ws;
    float* m1 = (float*)d_ws + 2649600;
    float* m2 = m1 + 524288;
    float* m3 = m2 + 131072;
    float* m4 = m3 + 32768;
    _Float16* P = (_Float16*)(m4 + 8192);
    _Float16* Q = P + 16777216;
    _Float16* R = Q + 16777216;

    size_t ro = 0;
    auto reord = [&](const float* wsrc, int Cin, int Cout) -> const _Float16* {
        _Float16* dst = rwbase + ro;
        int total = Cout * Cin * 9;
        reorder_w<<<(total + 255) / 256, 256, 0, stream>>>(wsrc, dst, Cin, Cout);
        ro += (size_t)total;
        return dst;
    };

    const _Float16* r1[5]; for (int i = 0; i < 5; ++i) r1[i] = reord(w1 + (size_t)i * 9216, 32, 32);
    const _Float16* rd2 = reord(wd2, 32, 64);
    const _Float16* r2[4]; for (int i = 0; i < 4; ++i) r2[i] = reord(w2 + (size_t)i * 36864, 64, 64);
    const _Float16* rd3 = reord(wd3, 64, 128);
    const _Float16* r3[4]; for (int i = 0; i < 4; ++i) r3[i] = reord(w3 + (size_t)i * 147456, 128, 128);
    const _Float16* rd4 = reord(wd4, 128, 256);
    const _Float16* r4[4]; for (int i = 0; i < 4; ++i) r4[i] = reord(w4 + (size_t)i * 589824, 256, 256);
    const _Float16* r5[3]; for (int i = 0; i < 3; ++i) r5[i] = reord(w5 + (size_t)i * 589824, 256, 256);

    // masks + x0 (fp16 blocked)
    {
        int n = B * 512 * 512;
        mask_make<<<(n + 255) / 256, 256, 0, stream>>>(x, mask_p, m1, P, B, 512 * 512);
        mask_down<<<(B * 256 * 256 + 255) / 256, 256, 0, stream>>>(m1, m2, B, 512, 512, 256, 256);
        mask_down<<<(B * 128 * 128 + 255) / 256, 256, 0, stream>>>(m2, m3, B, 256, 256, 128, 128);
        mask_down<<<(B * 64 * 64 + 255) / 256, 256, 0, stream>>>(m3, m4, B, 128, 128, 64, 64);
    }

    auto conv = [&](const _Float16* in, const _Float16* rwp, const float* sp, const float* tp,
                    const float* mk, const _Float16* rs, float* o32, _Float16* o16,
                    int Cin, int Cout, int Hin, int Win, int stride, int BM, int BN) {
        int Hout = Hin / stride, Wout = Win / stride, HWo = Hout * Wout;
        int TW = (Wout < BN) ? Wout : BN;
        int TH = BN / TW;
        dim3 grid(HWo / BN, Cout / BM, B);
        if (BM == 32 && BN == 256)
            conv_mfma<32, 256><<<grid, 256, 0, stream>>>(in, rwp, sp, tp, mk, rs, o32, o16,
                Cin, Cout, Hin, Win, Hout, Wout, TH, TW, stride, 1);
        else if (BM == 64 && BN == 128)
            conv_mfma<64, 128><<<grid, 256, 0, stream>>>(in, rwp, sp, tp, mk, rs, o32, o16,
                Cin, Cout, Hin, Win, Hout, Wout, TH, TW, stride, 1);
        else if (BM == 128 && BN == 64)
            conv_mfma<128, 64><<<grid, 256, 0, stream>>>(in, rwp, sp, tp, mk, rs, o32, o16,
                Cin, Cout, Hin, Win, Hout, Wout, TH, TW, stride, 1);
        else
            conv_mfma<64, 64><<<grid, 256, 0, stream>>>(in, rwp, sp, tp, mk, rs, o32, o16,
                Cin, Cout, Hin, Win, Hout, Wout, TH, TW, stride, 1);
    };

    // ---- stage 1 (32ch, 512x512) ----
    conv(P, r1[0], s1 + 0,   t1 + 0,   m1, nullptr, nullptr, Q, 32, 32, 512, 512, 1, 32, 256);
    conv(Q, r1[1], s1 + 32,  t1 + 32,  m1, nullptr, nullptr, R, 32, 32, 512, 512, 1, 32, 256);
    conv(R, r1[2], s1 + 64,  t1 + 64,  m1, Q,       nullptr, P, 32, 32, 512, 512, 1, 32, 256);
    conv(P, r1[3], s1 + 96,  t1 + 96,  m1, nullptr, nullptr, Q, 32, 32, 512, 512, 1, 32, 256);
    conv(Q, r1[4], s1 + 128, t1 + 128, m1, P,       x1o,     R, 32, 32, 512, 512, 1, 32, 256);

    // ---- stage 2 (32->64, 512->256): X1 = R ----
    conv(R, rd2,   s2 + 0,   t2 + 0,   m2, nullptr, nullptr, P, 32, 64, 512, 512, 2, 64, 128);
    conv(P, r2[0], s2 + 64,  t2 + 64,  m2, nullptr, nullptr, Q, 64, 64, 256, 256, 1, 64, 128);
    conv(Q, r2[1], s2 + 128, t2 + 128, m2, P,       nullptr, P, 64, 64, 256, 256, 1, 64, 128);
    conv(P, r2[2], s2 + 192, t2 + 192, m2, nullptr, nullptr, Q, 64, 64, 256, 256, 1, 64, 128);
    conv(Q, r2[3], s2 + 256, t2 + 256, m2, P,       x2o,     P, 64, 64, 256, 256, 1, 64, 128);

    // ---- stage 3 (64->128, 256->128): X2 = P ----
    conv(P, rd3,   s3 + 0,   t3 + 0,   m3, nullptr, nullptr, Q, 64, 128, 256, 256, 2, 128, 64);
    conv(Q, r3[0], s3 + 128, t3 + 128, m3, nullptr, nullptr, R, 128, 128, 128, 128, 1, 128, 64);
    conv(R, r3[1], s3 + 256, t3 + 256, m3, Q,       nullptr, Q, 128, 128, 128, 128, 1, 128, 64);
    conv(Q, r3[2], s3 + 384, t3 + 384, m3, nullptr, nullptr, R, 128, 128, 128, 128, 1, 128, 64);
    conv(R, r3[3], s3 + 512, t3 + 512, m3, Q,       x3o,     Q, 128, 128, 128, 128, 1, 128, 64);

    // ---- stage 4 (128->256, 128->64): X3 = Q ----
    conv(Q, rd4,   s4 + 0,    t4 + 0,    m4, nullptr, nullptr, P, 128, 256, 128, 128, 2, 64, 64);
    conv(P, r4[0], s4 + 256,  t4 + 256,  m4, nullptr, nullptr, R, 256, 256, 64, 64, 1, 64, 64);
    conv(R, r4[1], s4 + 512,  t4 + 512,  m4, P,       nullptr, P, 256, 256, 64, 64, 1, 64, 64);
    conv(P, r4[2], s4 + 768,  t4 + 768,  m4, nullptr, nullptr, R, 256, 256, 64, 64, 1, 64, 64);
    conv(R, r4[3], s4 + 1024, t4 + 1024, m4, P,       x4o,     P, 256, 256, 64, 64, 1, 64, 64);

    // ---- conv5 (dense): X4 = P ----
    conv(P, r5[0], s5 + 0,   t5 + 0,   nullptr, nullptr, nullptr, Q, 256, 256, 64, 64, 2, 64, 64);
    conv(Q, r5[1], s5 + 256, t5 + 256, nullptr, nullptr, nullptr, R, 256, 256, 32, 32, 1, 64, 64);
    conv(R, r5[2], s5 + 512, t5 + 512, nullptr, nullptr, x5o, nullptr, 256, 256, 32, 32, 1, 64, 64);
}